// Round 13
// baseline (363.740 us; speedup 1.0000x reference)
//
#include <hip/hip_runtime.h>
#include <math.h>

// Problem constants (from reference): N=2e6, C=64, B=16, H=32.
#define NCH   64
#define NBAT  16
#define NHID  32
#define NBLK  1024   // chunk count shared by pool and apply (1:1 mapping)

typedef float    f4 __attribute__((ext_vector_type(4)));
typedef float    f8 __attribute__((ext_vector_type(8)));
typedef _Float16 h4 __attribute__((ext_vector_type(4)));
typedef _Float16 h8 __attribute__((ext_vector_type(8)));

// Workspace layout:
//   floats [0    .. 1023]  per-(b,c) sums
//   floats [1024 .. 2047]  per-(b,c) maxes
//   floats [2064 .. 3087]  per-(b,c) scale = 1 + sigmoid(mlp(avg)+mlp(max))
//   byte 16384 ...         fp16 staging copy of x (n*64*2 bytes), if ws fits

__device__ __forceinline__ void atomicMaxF(float* addr, float v) {
    // Monotone-lattice trick: works for mixed signs, init must be -inf.
    if (v >= 0.0f) atomicMax((int*)addr, __float_as_int(v));
    else           atomicMin((unsigned int*)addr, __float_as_uint(v));
}

__device__ __forceinline__ f4 vmax4(f4 a, f4 b) {
    f4 r;
    r.x = fmaxf(a.x, b.x); r.y = fmaxf(a.y, b.y);
    r.z = fmaxf(a.z, b.z); r.w = fmaxf(a.w, b.w);
    return r;
}

// First index i with a[i] >= v (a sorted ascending).
__device__ __forceinline__ int lower_bound_i(const int* __restrict__ a, int n, int v) {
    int lo = 0, hi = n;
    while (lo < hi) {
        const int mid = (lo + hi) >> 1;
        if (a[mid] < v) lo = mid + 1; else hi = mid;
    }
    return lo;
}

__global__ __launch_bounds__(256) void init_kernel(float* ws) {
    const int i = blockIdx.x * blockDim.x + threadIdx.x;
    if (i < 1024) {
        ws[i] = 0.0f;                  // sums
        ws[1024 + i] = -INFINITY;      // maxes
    }
}

// ---------------- staged path (fp16 L3-resident copy) ----------------

// Pool + stage: NT-load fp32 x (no L3 allocation -> doesn't evict xh),
// accumulate seg sum/max, store fp16 copy with NORMAL stores (allocates in
// the memory-side Infinity Cache; 256 MB = L3-sized, stays hot).
__global__ __launch_bounds__(256) void pool_stage_kernel(const float* __restrict__ x,
                                                         const int* __restrict__ bid,
                                                         float* __restrict__ wsum,
                                                         float* __restrict__ wmax,
                                                         _Float16* __restrict__ xh,
                                                         int n, int rpb) {
    __shared__ int sstart[NBAT + 1];
    __shared__ f4 ls[256];
    __shared__ f4 lm[256];
    const int t = threadIdx.x;
    if (t <= NBAT) sstart[t] = (t == NBAT) ? n : lower_bound_i(bid, n, t);
    __syncthreads();

    const int c4 = t & 15;
    const int rg = t >> 4;
    const int r0 = blockIdx.x * rpb;
    const int rend = min(r0 + rpb, n);
    const f4 fzero = {0.f, 0.f, 0.f, 0.f};
    const f4 fninf = {-INFINITY, -INFINITY, -INFINITY, -INFINITY};

    for (int b = 0; b < NBAT; ++b) {
        const int lo = max(sstart[b], r0);
        const int hi = min(sstart[b + 1], rend);
        if (lo >= hi) continue;                 // block-uniform

        f4 s = fzero, m = fninf;
        const int base = lo + rg;
        const int k = (hi > base) ? ((hi - base + 15) >> 4) : 0;
        const float* xp = x + (size_t)base * NCH + c4 * 4;
        _Float16* hp = xh + (size_t)base * NCH + c4 * 4;
        int j = 0;
        for (; j + 4 <= k; j += 4) {
            const f4 v0 = __builtin_nontemporal_load(reinterpret_cast<const f4*>(xp + (size_t)(j + 0) * 16 * NCH));
            const f4 v1 = __builtin_nontemporal_load(reinterpret_cast<const f4*>(xp + (size_t)(j + 1) * 16 * NCH));
            const f4 v2 = __builtin_nontemporal_load(reinterpret_cast<const f4*>(xp + (size_t)(j + 2) * 16 * NCH));
            const f4 v3 = __builtin_nontemporal_load(reinterpret_cast<const f4*>(xp + (size_t)(j + 3) * 16 * NCH));
            s += v0; s += v1; s += v2; s += v3;
            m = vmax4(m, vmax4(vmax4(v0, v1), vmax4(v2, v3)));
            *reinterpret_cast<h4*>(hp + (size_t)(j + 0) * 16 * NCH) = __builtin_convertvector(v0, h4);
            *reinterpret_cast<h4*>(hp + (size_t)(j + 1) * 16 * NCH) = __builtin_convertvector(v1, h4);
            *reinterpret_cast<h4*>(hp + (size_t)(j + 2) * 16 * NCH) = __builtin_convertvector(v2, h4);
            *reinterpret_cast<h4*>(hp + (size_t)(j + 3) * 16 * NCH) = __builtin_convertvector(v3, h4);
        }
        for (; j < k; ++j) {
            const f4 v = __builtin_nontemporal_load(reinterpret_cast<const f4*>(xp + (size_t)j * 16 * NCH));
            s += v; m = vmax4(m, v);
            *reinterpret_cast<h4*>(hp + (size_t)j * 16 * NCH) = __builtin_convertvector(v, h4);
        }

        // Block combine across the 16 row groups (same c4), then 8 atomics.
        ls[t] = s; lm[t] = m;
        __syncthreads();
        if (rg == 0) {
            for (int gg = 1; gg < 16; ++gg) {
                s += ls[gg * 16 + c4];
                m = vmax4(m, lm[gg * 16 + c4]);
            }
            float* ps = wsum + b * NCH + c4 * 4;
            atomicAdd(ps + 0, s.x);
            atomicAdd(ps + 1, s.y);
            atomicAdd(ps + 2, s.z);
            atomicAdd(ps + 3, s.w);
            float* pm = wmax + b * NCH + c4 * 4;
            atomicMaxF(pm + 0, m.x);
            atomicMaxF(pm + 1, m.y);
            atomicMaxF(pm + 2, m.z);
            atomicMaxF(pm + 3, m.w);
        }
        __syncthreads();   // ls/lm reused by next segment
    }
}

// Apply from the fp16 staging copy (L3-resident -> reads mostly L3 hits).
// h8 = 16 B/lane loads (8 channels), 32 rows/iteration, NT f8 stores.
// Scale comes precomputed from the 1-block mlp_kernel (the R12 fold of the
// MLP into this kernel multiplied its stride-64 weight gather by 1024 blocks
// and cost +85 us -- keep the MLP separate).
__global__ __launch_bounds__(256) void apply_stage_kernel(const _Float16* __restrict__ xh,
                                                          const int* __restrict__ bid,
                                                          const float* __restrict__ scale,
                                                          float* __restrict__ out,
                                                          int n, int rpb) {
    __shared__ int   sstart[NBAT + 1];
    __shared__ float s_scale[NBAT * NCH];
    const int t = threadIdx.x;
    if (t <= NBAT) sstart[t] = (t == NBAT) ? n : lower_bound_i(bid, n, t);
    for (int i = t; i < NBAT * NCH; i += 256) s_scale[i] = scale[i];
    __syncthreads();

    const int c8 = t & 7;    // 8 channels per lane (16 B fp16)
    const int rg = t >> 3;   // 32 rows in flight
    const int r0 = blockIdx.x * rpb;
    const int rend = min(r0 + rpb, n);

    for (int b = 0; b < NBAT; ++b) {
        const int lo = max(sstart[b], r0);
        const int hi = min(sstart[b + 1], rend);
        if (lo >= hi) continue;                 // block-uniform

        const f8 sc = *reinterpret_cast<const f8*>(s_scale + b * NCH + c8 * 8);
        const int base = lo + rg;
        const int k = (hi > base) ? ((hi - base + 31) >> 5) : 0;
        const _Float16* hp = xh + (size_t)base * NCH + c8 * 8;
        float* op = out + (size_t)base * NCH + c8 * 8;

        int j = 0;
        for (; j + 4 <= k; j += 4) {
            h8 u0 = *reinterpret_cast<const h8*>(hp + (size_t)(j + 0) * 32 * NCH);
            h8 u1 = *reinterpret_cast<const h8*>(hp + (size_t)(j + 1) * 32 * NCH);
            h8 u2 = *reinterpret_cast<const h8*>(hp + (size_t)(j + 2) * 32 * NCH);
            h8 u3 = *reinterpret_cast<const h8*>(hp + (size_t)(j + 3) * 32 * NCH);
            __builtin_nontemporal_store(__builtin_convertvector(u0, f8) * sc,
                                        reinterpret_cast<f8*>(op + (size_t)(j + 0) * 32 * NCH));
            __builtin_nontemporal_store(__builtin_convertvector(u1, f8) * sc,
                                        reinterpret_cast<f8*>(op + (size_t)(j + 1) * 32 * NCH));
            __builtin_nontemporal_store(__builtin_convertvector(u2, f8) * sc,
                                        reinterpret_cast<f8*>(op + (size_t)(j + 2) * 32 * NCH));
            __builtin_nontemporal_store(__builtin_convertvector(u3, f8) * sc,
                                        reinterpret_cast<f8*>(op + (size_t)(j + 3) * 32 * NCH));
        }
        for (; j < k; ++j) {
            const h8 u = *reinterpret_cast<const h8*>(hp + (size_t)j * 32 * NCH);
            __builtin_nontemporal_store(__builtin_convertvector(u, f8) * sc,
                                        reinterpret_cast<f8*>(op + (size_t)j * 32 * NCH));
        }
    }
}

// ---------------- fallback path (R8, no staging) ----------------

__global__ __launch_bounds__(256) void pool_kernel(const float* __restrict__ x,
                                                   const int* __restrict__ bid,
                                                   float* __restrict__ wsum,
                                                   float* __restrict__ wmax,
                                                   int n, int rpb) {
    __shared__ int sstart[NBAT + 1];
    __shared__ f4 ls[256];
    __shared__ f4 lm[256];
    const int t = threadIdx.x;
    if (t <= NBAT) sstart[t] = (t == NBAT) ? n : lower_bound_i(bid, n, t);
    __syncthreads();

    const int c4 = t & 15;
    const int rg = t >> 4;
    const int r0 = blockIdx.x * rpb;
    const int rend = min(r0 + rpb, n);
    const f4 fzero = {0.f, 0.f, 0.f, 0.f};
    const f4 fninf = {-INFINITY, -INFINITY, -INFINITY, -INFINITY};

    for (int b = 0; b < NBAT; ++b) {
        const int lo = max(sstart[b], r0);
        const int hi = min(sstart[b + 1], rend);
        if (lo >= hi) continue;

        f4 s = fzero, m = fninf;
        const int base = lo + rg;
        const int k = (hi > base) ? ((hi - base + 15) >> 4) : 0;
        const float* xp = x + (size_t)base * NCH + c4 * 4;
        int j = 0;
        for (; j + 4 <= k; j += 4) {
            const f4 v0 = *reinterpret_cast<const f4*>(xp + (size_t)(j + 0) * 16 * NCH);
            const f4 v1 = *reinterpret_cast<const f4*>(xp + (size_t)(j + 1) * 16 * NCH);
            const f4 v2 = *reinterpret_cast<const f4*>(xp + (size_t)(j + 2) * 16 * NCH);
            const f4 v3 = *reinterpret_cast<const f4*>(xp + (size_t)(j + 3) * 16 * NCH);
            s += v0; s += v1; s += v2; s += v3;
            m = vmax4(m, vmax4(vmax4(v0, v1), vmax4(v2, v3)));
        }
        for (; j < k; ++j) {
            const f4 v = *reinterpret_cast<const f4*>(xp + (size_t)j * 16 * NCH);
            s += v; m = vmax4(m, v);
        }

        ls[t] = s; lm[t] = m;
        __syncthreads();
        if (rg == 0) {
            for (int gg = 1; gg < 16; ++gg) {
                s += ls[gg * 16 + c4];
                m = vmax4(m, lm[gg * 16 + c4]);
            }
            float* ps = wsum + b * NCH + c4 * 4;
            atomicAdd(ps + 0, s.x);
            atomicAdd(ps + 1, s.y);
            atomicAdd(ps + 2, s.z);
            atomicAdd(ps + 3, s.w);
            float* pm = wmax + b * NCH + c4 * 4;
            atomicMaxF(pm + 0, m.x);
            atomicMaxF(pm + 1, m.y);
            atomicMaxF(pm + 2, m.z);
            atomicMaxF(pm + 3, m.w);
        }
        __syncthreads();
    }
}

__global__ __launch_bounds__(256) void apply_kernel(const float* __restrict__ x,
                                                    const int* __restrict__ bid,
                                                    const float* __restrict__ scale,
                                                    float* __restrict__ out,
                                                    int n, int rpb) {
    __shared__ int   sstart[NBAT + 1];
    __shared__ float s_scale[NBAT * NCH];
    const int t = threadIdx.x;
    if (t <= NBAT) sstart[t] = (t == NBAT) ? n : lower_bound_i(bid, n, t);
    for (int i = t; i < NBAT * NCH; i += 256) s_scale[i] = scale[i];
    __syncthreads();

    const int c4 = t & 15;
    const int rg = t >> 4;
    const int r0 = blockIdx.x * rpb;
    const int rend = min(r0 + rpb, n);

    for (int b = NBAT - 1; b >= 0; --b) {
        const int lo = max(sstart[b], r0);
        const int hi = min(sstart[b + 1], rend);
        if (lo >= hi) continue;

        const f4 sc = *reinterpret_cast<const f4*>(s_scale + b * NCH + c4 * 4);
        const int base = lo + rg;
        int k = (hi > base) ? ((hi - base + 15) >> 4) : 0;
        const float* xp = x + (size_t)base * NCH + c4 * 4;
        float* op = out + (size_t)base * NCH + c4 * 4;

        while (k >= 4) {
            k -= 4;
            const f4 v0 = *reinterpret_cast<const f4*>(xp + (size_t)(k + 0) * 16 * NCH);
            const f4 v1 = *reinterpret_cast<const f4*>(xp + (size_t)(k + 1) * 16 * NCH);
            const f4 v2 = *reinterpret_cast<const f4*>(xp + (size_t)(k + 2) * 16 * NCH);
            const f4 v3 = *reinterpret_cast<const f4*>(xp + (size_t)(k + 3) * 16 * NCH);
            __builtin_nontemporal_store(v0 * sc, reinterpret_cast<f4*>(op + (size_t)(k + 0) * 16 * NCH));
            __builtin_nontemporal_store(v1 * sc, reinterpret_cast<f4*>(op + (size_t)(k + 1) * 16 * NCH));
            __builtin_nontemporal_store(v2 * sc, reinterpret_cast<f4*>(op + (size_t)(k + 2) * 16 * NCH));
            __builtin_nontemporal_store(v3 * sc, reinterpret_cast<f4*>(op + (size_t)(k + 3) * 16 * NCH));
        }
        while (k > 0) {
            --k;
            const f4 v = *reinterpret_cast<const f4*>(xp + (size_t)k * 16 * NCH);
            __builtin_nontemporal_store(v * sc, reinterpret_cast<f4*>(op + (size_t)k * 16 * NCH));
        }
    }
}

// ---------------- shared MLP (1 block) ----------------

__global__ __launch_bounds__(512) void mlp_kernel(const float* __restrict__ ws,
                                                  const int* __restrict__ bid,
                                                  const float* __restrict__ W1,
                                                  const float* __restrict__ b1,
                                                  const float* __restrict__ W2,
                                                  const float* __restrict__ b2,
                                                  float* __restrict__ scale_out,
                                                  int n) {
    __shared__ int   sstart[NBAT + 1];
    __shared__ float avg[NBAT * NCH];
    __shared__ float mxs[NBAT * NCH];
    __shared__ float h1a[NBAT * NHID];
    __shared__ float h1m[NBAT * NHID];
    const int t = threadIdx.x;
    if (t <= NBAT) sstart[t] = (t == NBAT) ? n : lower_bound_i(bid, n, t);
    __syncthreads();

    for (int i = t; i < NBAT * NCH; i += 512) {
        const int b = i >> 6;
        const float c = (float)(sstart[b + 1] - sstart[b]);
        avg[i] = ws[i] / fmaxf(c, 1.0f);
        mxs[i] = ws[1024 + i];
    }
    __syncthreads();

    {   // h1 = relu(h @ W1.T + b1), both branches. 512 threads = 16b x 32j.
        const int b = t >> 5, j = t & 31;
        float sa = b1[j], sm = b1[j];
        const float* w = W1 + j * NCH;
        for (int c = 0; c < NCH; ++c) {
            const float wv = w[c];
            sa += avg[b * NCH + c] * wv;
            sm += mxs[b * NCH + c] * wv;
        }
        h1a[b * NHID + j] = fmaxf(sa, 0.0f);
        h1m[b * NHID + j] = fmaxf(sm, 0.0f);
    }
    __syncthreads();

    for (int i = t; i < NBAT * NCH; i += 512) {
        const int b = i >> 6, c = i & 63;
        float ya = b2[c], ym = b2[c];
        const float* w = W2 + c * NHID;
        for (int j = 0; j < NHID; ++j) {
            const float wv = w[j];
            ya += h1a[b * NHID + j] * wv;
            ym += h1m[b * NHID + j] * wv;
        }
        const float z = ya + ym;
        const float sig = 1.0f / (1.0f + expf(-z));
        scale_out[i] = 1.0f + sig;  // out = x*att + x = x*(1+att)
    }
}

extern "C" void kernel_launch(void* const* d_in, const int* in_sizes, int n_in,
                              void* d_out, int out_size, void* d_ws, size_t ws_size,
                              hipStream_t stream) {
    const float* x   = (const float*)d_in[0];
    const int*   bid = (const int*)d_in[1];
    const float* W1  = (const float*)d_in[2];
    const float* b1  = (const float*)d_in[3];
    const float* W2  = (const float*)d_in[4];
    const float* b2  = (const float*)d_in[5];
    float* out = (float*)d_out;
    const int n = in_sizes[1];  // N (batch_ids element count)

    float* ws     = (float*)d_ws;
    float* wsum   = ws;
    float* wmax   = ws + 1024;
    float* wscale = ws + 2064;
    _Float16* xh  = (_Float16*)((char*)d_ws + 16384);

    const size_t need = 16384 + (size_t)n * NCH * sizeof(_Float16);
    const bool staged = (ws_size >= need);

    hipLaunchKernelGGL(init_kernel, dim3(4), dim3(256), 0, stream, ws);

    const int rpb = (n + NBLK - 1) / NBLK;
    if (staged) {
        hipLaunchKernelGGL(pool_stage_kernel, dim3(NBLK), dim3(256), 0, stream,
                           x, bid, wsum, wmax, xh, n, rpb);
        hipLaunchKernelGGL(mlp_kernel, dim3(1), dim3(512), 0, stream,
                           ws, bid, W1, b1, W2, b2, wscale, n);
        hipLaunchKernelGGL(apply_stage_kernel, dim3(NBLK), dim3(256), 0, stream,
                           xh, bid, wscale, out, n, rpb);
    } else {
        hipLaunchKernelGGL(pool_kernel, dim3(NBLK), dim3(256), 0, stream,
                           x, bid, wsum, wmax, n, rpb);
        hipLaunchKernelGGL(mlp_kernel, dim3(1), dim3(512), 0, stream,
                           ws, bid, W1, b1, W2, b2, wscale, n);
        hipLaunchKernelGGL(apply_kernel, dim3(NBLK), dim3(256), 0, stream,
                           x, bid, wscale, out, n, rpb);
    }
}

// Round 14
// 275.316 us; speedup vs baseline: 1.3212x; 1.3212x over previous
//
#include <hip/hip_runtime.h>
#include <math.h>

// Problem constants (from reference): N=2e6, C=64, B=16, H=32.
#define NCH   64
#define NBAT  16
#define NHID  32
#define NBLK  1024   // chunk count shared by pool and apply (1:1 mapping)

typedef float    f4 __attribute__((ext_vector_type(4)));
typedef _Float16 h4 __attribute__((ext_vector_type(4)));

// Workspace layout:
//   floats [0    .. 1023]  per-(b,c) sums
//   floats [1024 .. 2047]  per-(b,c) maxes
//   floats [2064 .. 3087]  per-(b,c) scale = 1 + sigmoid(mlp(avg)+mlp(max))
//   byte 16384 ...         fp16 staging copy of x (n*64*2 bytes), if ws fits

__device__ __forceinline__ void atomicMaxF(float* addr, float v) {
    // Monotone-lattice trick: works for mixed signs, init must be -inf.
    if (v >= 0.0f) atomicMax((int*)addr, __float_as_int(v));
    else           atomicMin((unsigned int*)addr, __float_as_uint(v));
}

__device__ __forceinline__ f4 vmax4(f4 a, f4 b) {
    f4 r;
    r.x = fmaxf(a.x, b.x); r.y = fmaxf(a.y, b.y);
    r.z = fmaxf(a.z, b.z); r.w = fmaxf(a.w, b.w);
    return r;
}

// First index i with a[i] >= v (a sorted ascending).
__device__ __forceinline__ int lower_bound_i(const int* __restrict__ a, int n, int v) {
    int lo = 0, hi = n;
    while (lo < hi) {
        const int mid = (lo + hi) >> 1;
        if (a[mid] < v) lo = mid + 1; else hi = mid;
    }
    return lo;
}

__global__ __launch_bounds__(256) void init_kernel(float* ws) {
    const int i = blockIdx.x * blockDim.x + threadIdx.x;
    if (i < 1024) {
        ws[i] = 0.0f;                  // sums
        ws[1024 + i] = -INFINITY;      // maxes
    }
}

// ---------------- staged path (fp16 L3-resident copy) ----------------

// Pool + stage: NT-load fp32 x (no L3 allocation -> doesn't evict xh),
// accumulate seg sum/max, store fp16 copy with NORMAL stores (allocates in
// the memory-side Infinity Cache; 256 MB = L3-sized, stays hot).
__global__ __launch_bounds__(256) void pool_stage_kernel(const float* __restrict__ x,
                                                         const int* __restrict__ bid,
                                                         float* __restrict__ wsum,
                                                         float* __restrict__ wmax,
                                                         _Float16* __restrict__ xh,
                                                         int n, int rpb) {
    __shared__ int sstart[NBAT + 1];
    __shared__ f4 ls[256];
    __shared__ f4 lm[256];
    const int t = threadIdx.x;
    if (t <= NBAT) sstart[t] = (t == NBAT) ? n : lower_bound_i(bid, n, t);
    __syncthreads();

    const int c4 = t & 15;
    const int rg = t >> 4;
    const int r0 = blockIdx.x * rpb;
    const int rend = min(r0 + rpb, n);
    const f4 fzero = {0.f, 0.f, 0.f, 0.f};
    const f4 fninf = {-INFINITY, -INFINITY, -INFINITY, -INFINITY};

    for (int b = 0; b < NBAT; ++b) {
        const int lo = max(sstart[b], r0);
        const int hi = min(sstart[b + 1], rend);
        if (lo >= hi) continue;                 // block-uniform

        f4 s = fzero, m = fninf;
        const int base = lo + rg;
        const int k = (hi > base) ? ((hi - base + 15) >> 4) : 0;
        const float* xp = x + (size_t)base * NCH + c4 * 4;
        _Float16* hp = xh + (size_t)base * NCH + c4 * 4;
        int j = 0;
        for (; j + 4 <= k; j += 4) {
            const f4 v0 = __builtin_nontemporal_load(reinterpret_cast<const f4*>(xp + (size_t)(j + 0) * 16 * NCH));
            const f4 v1 = __builtin_nontemporal_load(reinterpret_cast<const f4*>(xp + (size_t)(j + 1) * 16 * NCH));
            const f4 v2 = __builtin_nontemporal_load(reinterpret_cast<const f4*>(xp + (size_t)(j + 2) * 16 * NCH));
            const f4 v3 = __builtin_nontemporal_load(reinterpret_cast<const f4*>(xp + (size_t)(j + 3) * 16 * NCH));
            s += v0; s += v1; s += v2; s += v3;
            m = vmax4(m, vmax4(vmax4(v0, v1), vmax4(v2, v3)));
            *reinterpret_cast<h4*>(hp + (size_t)(j + 0) * 16 * NCH) = __builtin_convertvector(v0, h4);
            *reinterpret_cast<h4*>(hp + (size_t)(j + 1) * 16 * NCH) = __builtin_convertvector(v1, h4);
            *reinterpret_cast<h4*>(hp + (size_t)(j + 2) * 16 * NCH) = __builtin_convertvector(v2, h4);
            *reinterpret_cast<h4*>(hp + (size_t)(j + 3) * 16 * NCH) = __builtin_convertvector(v3, h4);
        }
        for (; j < k; ++j) {
            const f4 v = __builtin_nontemporal_load(reinterpret_cast<const f4*>(xp + (size_t)j * 16 * NCH));
            s += v; m = vmax4(m, v);
            *reinterpret_cast<h4*>(hp + (size_t)j * 16 * NCH) = __builtin_convertvector(v, h4);
        }

        // Block combine across the 16 row groups (same c4), then 8 atomics.
        ls[t] = s; lm[t] = m;
        __syncthreads();
        if (rg == 0) {
            for (int gg = 1; gg < 16; ++gg) {
                s += ls[gg * 16 + c4];
                m = vmax4(m, lm[gg * 16 + c4]);
            }
            float* ps = wsum + b * NCH + c4 * 4;
            atomicAdd(ps + 0, s.x);
            atomicAdd(ps + 1, s.y);
            atomicAdd(ps + 2, s.z);
            atomicAdd(ps + 3, s.w);
            float* pm = wmax + b * NCH + c4 * 4;
            atomicMaxF(pm + 0, m.x);
            atomicMaxF(pm + 1, m.y);
            atomicMaxF(pm + 2, m.z);
            atomicMaxF(pm + 3, m.w);
        }
        __syncthreads();   // ls/lm reused by next segment
    }
}

// Apply from the fp16 staging copy (L3-resident -> reads mostly L3 hits).
// Normal loads (want cache), NT stores for out. x8 unroll (8B loads).
// NOTE: keep NT accesses <= 16 B/lane -- f8/h8 NT ops scalarize (R13: +90us).
__global__ __launch_bounds__(256) void apply_stage_kernel(const _Float16* __restrict__ xh,
                                                          const int* __restrict__ bid,
                                                          const float* __restrict__ scale,
                                                          float* __restrict__ out,
                                                          int n, int rpb) {
    __shared__ int   sstart[NBAT + 1];
    __shared__ float s_scale[NBAT * NCH];
    const int t = threadIdx.x;
    if (t <= NBAT) sstart[t] = (t == NBAT) ? n : lower_bound_i(bid, n, t);
    for (int i = t; i < NBAT * NCH; i += 256) s_scale[i] = scale[i];
    __syncthreads();

    const int c4 = t & 15;
    const int rg = t >> 4;
    const int r0 = blockIdx.x * rpb;
    const int rend = min(r0 + rpb, n);

    for (int b = 0; b < NBAT; ++b) {
        const int lo = max(sstart[b], r0);
        const int hi = min(sstart[b + 1], rend);
        if (lo >= hi) continue;                 // block-uniform

        const f4 sc = *reinterpret_cast<const f4*>(s_scale + b * NCH + c4 * 4);
        const int base = lo + rg;
        const int k = (hi > base) ? ((hi - base + 15) >> 4) : 0;
        const _Float16* hp = xh + (size_t)base * NCH + c4 * 4;
        float* op = out + (size_t)base * NCH + c4 * 4;

        int j = 0;
        for (; j + 8 <= k; j += 8) {
            h4 u[8];
#pragma unroll
            for (int q = 0; q < 8; ++q)
                u[q] = *reinterpret_cast<const h4*>(hp + (size_t)(j + q) * 16 * NCH);
#pragma unroll
            for (int q = 0; q < 8; ++q) {
                const f4 v = __builtin_convertvector(u[q], f4) * sc;
                __builtin_nontemporal_store(v, reinterpret_cast<f4*>(op + (size_t)(j + q) * 16 * NCH));
            }
        }
        for (; j < k; ++j) {
            const h4 u = *reinterpret_cast<const h4*>(hp + (size_t)j * 16 * NCH);
            const f4 v = __builtin_convertvector(u, f4) * sc;
            __builtin_nontemporal_store(v, reinterpret_cast<f4*>(op + (size_t)j * 16 * NCH));
        }
    }
}

// ---------------- fallback path (R8, no staging) ----------------

__global__ __launch_bounds__(256) void pool_kernel(const float* __restrict__ x,
                                                   const int* __restrict__ bid,
                                                   float* __restrict__ wsum,
                                                   float* __restrict__ wmax,
                                                   int n, int rpb) {
    __shared__ int sstart[NBAT + 1];
    __shared__ f4 ls[256];
    __shared__ f4 lm[256];
    const int t = threadIdx.x;
    if (t <= NBAT) sstart[t] = (t == NBAT) ? n : lower_bound_i(bid, n, t);
    __syncthreads();

    const int c4 = t & 15;
    const int rg = t >> 4;
    const int r0 = blockIdx.x * rpb;
    const int rend = min(r0 + rpb, n);
    const f4 fzero = {0.f, 0.f, 0.f, 0.f};
    const f4 fninf = {-INFINITY, -INFINITY, -INFINITY, -INFINITY};

    for (int b = 0; b < NBAT; ++b) {
        const int lo = max(sstart[b], r0);
        const int hi = min(sstart[b + 1], rend);
        if (lo >= hi) continue;

        f4 s = fzero, m = fninf;
        const int base = lo + rg;
        const int k = (hi > base) ? ((hi - base + 15) >> 4) : 0;
        const float* xp = x + (size_t)base * NCH + c4 * 4;
        int j = 0;
        for (; j + 4 <= k; j += 4) {
            const f4 v0 = *reinterpret_cast<const f4*>(xp + (size_t)(j + 0) * 16 * NCH);
            const f4 v1 = *reinterpret_cast<const f4*>(xp + (size_t)(j + 1) * 16 * NCH);
            const f4 v2 = *reinterpret_cast<const f4*>(xp + (size_t)(j + 2) * 16 * NCH);
            const f4 v3 = *reinterpret_cast<const f4*>(xp + (size_t)(j + 3) * 16 * NCH);
            s += v0; s += v1; s += v2; s += v3;
            m = vmax4(m, vmax4(vmax4(v0, v1), vmax4(v2, v3)));
        }
        for (; j < k; ++j) {
            const f4 v = *reinterpret_cast<const f4*>(xp + (size_t)j * 16 * NCH);
            s += v; m = vmax4(m, v);
        }

        ls[t] = s; lm[t] = m;
        __syncthreads();
        if (rg == 0) {
            for (int gg = 1; gg < 16; ++gg) {
                s += ls[gg * 16 + c4];
                m = vmax4(m, lm[gg * 16 + c4]);
            }
            float* ps = wsum + b * NCH + c4 * 4;
            atomicAdd(ps + 0, s.x);
            atomicAdd(ps + 1, s.y);
            atomicAdd(ps + 2, s.z);
            atomicAdd(ps + 3, s.w);
            float* pm = wmax + b * NCH + c4 * 4;
            atomicMaxF(pm + 0, m.x);
            atomicMaxF(pm + 1, m.y);
            atomicMaxF(pm + 2, m.z);
            atomicMaxF(pm + 3, m.w);
        }
        __syncthreads();
    }
}

__global__ __launch_bounds__(256) void apply_kernel(const float* __restrict__ x,
                                                    const int* __restrict__ bid,
                                                    const float* __restrict__ scale,
                                                    float* __restrict__ out,
                                                    int n, int rpb) {
    __shared__ int   sstart[NBAT + 1];
    __shared__ float s_scale[NBAT * NCH];
    const int t = threadIdx.x;
    if (t <= NBAT) sstart[t] = (t == NBAT) ? n : lower_bound_i(bid, n, t);
    for (int i = t; i < NBAT * NCH; i += 256) s_scale[i] = scale[i];
    __syncthreads();

    const int c4 = t & 15;
    const int rg = t >> 4;
    const int r0 = blockIdx.x * rpb;
    const int rend = min(r0 + rpb, n);

    for (int b = NBAT - 1; b >= 0; --b) {
        const int lo = max(sstart[b], r0);
        const int hi = min(sstart[b + 1], rend);
        if (lo >= hi) continue;

        const f4 sc = *reinterpret_cast<const f4*>(s_scale + b * NCH + c4 * 4);
        const int base = lo + rg;
        int k = (hi > base) ? ((hi - base + 15) >> 4) : 0;
        const float* xp = x + (size_t)base * NCH + c4 * 4;
        float* op = out + (size_t)base * NCH + c4 * 4;

        while (k >= 4) {
            k -= 4;
            const f4 v0 = *reinterpret_cast<const f4*>(xp + (size_t)(k + 0) * 16 * NCH);
            const f4 v1 = *reinterpret_cast<const f4*>(xp + (size_t)(k + 1) * 16 * NCH);
            const f4 v2 = *reinterpret_cast<const f4*>(xp + (size_t)(k + 2) * 16 * NCH);
            const f4 v3 = *reinterpret_cast<const f4*>(xp + (size_t)(k + 3) * 16 * NCH);
            __builtin_nontemporal_store(v0 * sc, reinterpret_cast<f4*>(op + (size_t)(k + 0) * 16 * NCH));
            __builtin_nontemporal_store(v1 * sc, reinterpret_cast<f4*>(op + (size_t)(k + 1) * 16 * NCH));
            __builtin_nontemporal_store(v2 * sc, reinterpret_cast<f4*>(op + (size_t)(k + 2) * 16 * NCH));
            __builtin_nontemporal_store(v3 * sc, reinterpret_cast<f4*>(op + (size_t)(k + 3) * 16 * NCH));
        }
        while (k > 0) {
            --k;
            const f4 v = *reinterpret_cast<const f4*>(xp + (size_t)k * 16 * NCH);
            __builtin_nontemporal_store(v * sc, reinterpret_cast<f4*>(op + (size_t)k * 16 * NCH));
        }
    }
}

// ---------------- shared MLP (1 block) ----------------

__global__ __launch_bounds__(512) void mlp_kernel(const float* __restrict__ ws,
                                                  const int* __restrict__ bid,
                                                  const float* __restrict__ W1,
                                                  const float* __restrict__ b1,
                                                  const float* __restrict__ W2,
                                                  const float* __restrict__ b2,
                                                  float* __restrict__ scale_out,
                                                  int n) {
    __shared__ int   sstart[NBAT + 1];
    __shared__ float avg[NBAT * NCH];
    __shared__ float mxs[NBAT * NCH];
    __shared__ float h1a[NBAT * NHID];
    __shared__ float h1m[NBAT * NHID];
    const int t = threadIdx.x;
    if (t <= NBAT) sstart[t] = (t == NBAT) ? n : lower_bound_i(bid, n, t);
    __syncthreads();

    for (int i = t; i < NBAT * NCH; i += 512) {
        const int b = i >> 6;
        const float c = (float)(sstart[b + 1] - sstart[b]);
        avg[i] = ws[i] / fmaxf(c, 1.0f);
        mxs[i] = ws[1024 + i];
    }
    __syncthreads();

    {   // h1 = relu(h @ W1.T + b1), both branches. 512 threads = 16b x 32j.
        const int b = t >> 5, j = t & 31;
        float sa = b1[j], sm = b1[j];
        const float* w = W1 + j * NCH;
        for (int c = 0; c < NCH; ++c) {
            const float wv = w[c];
            sa += avg[b * NCH + c] * wv;
            sm += mxs[b * NCH + c] * wv;
        }
        h1a[b * NHID + j] = fmaxf(sa, 0.0f);
        h1m[b * NHID + j] = fmaxf(sm, 0.0f);
    }
    __syncthreads();

    for (int i = t; i < NBAT * NCH; i += 512) {
        const int b = i >> 6, c = i & 63;
        float ya = b2[c], ym = b2[c];
        const float* w = W2 + c * NHID;
        for (int j = 0; j < NHID; ++j) {
            const float wv = w[j];
            ya += h1a[b * NHID + j] * wv;
            ym += h1m[b * NHID + j] * wv;
        }
        const float z = ya + ym;
        const float sig = 1.0f / (1.0f + expf(-z));
        scale_out[i] = 1.0f + sig;  // out = x*att + x = x*(1+att)
    }
}

extern "C" void kernel_launch(void* const* d_in, const int* in_sizes, int n_in,
                              void* d_out, int out_size, void* d_ws, size_t ws_size,
                              hipStream_t stream) {
    const float* x   = (const float*)d_in[0];
    const int*   bid = (const int*)d_in[1];
    const float* W1  = (const float*)d_in[2];
    const float* b1  = (const float*)d_in[3];
    const float* W2  = (const float*)d_in[4];
    const float* b2  = (const float*)d_in[5];
    float* out = (float*)d_out;
    const int n = in_sizes[1];  // N (batch_ids element count)

    float* ws     = (float*)d_ws;
    float* wsum   = ws;
    float* wmax   = ws + 1024;
    float* wscale = ws + 2064;
    _Float16* xh  = (_Float16*)((char*)d_ws + 16384);

    const size_t need = 16384 + (size_t)n * NCH * sizeof(_Float16);
    const bool staged = (ws_size >= need);

    hipLaunchKernelGGL(init_kernel, dim3(4), dim3(256), 0, stream, ws);

    const int rpb = (n + NBLK - 1) / NBLK;
    if (staged) {
        hipLaunchKernelGGL(pool_stage_kernel, dim3(NBLK), dim3(256), 0, stream,
                           x, bid, wsum, wmax, xh, n, rpb);
        hipLaunchKernelGGL(mlp_kernel, dim3(1), dim3(512), 0, stream,
                           ws, bid, W1, b1, W2, b2, wscale, n);
        hipLaunchKernelGGL(apply_stage_kernel, dim3(NBLK), dim3(256), 0, stream,
                           xh, bid, wscale, out, n, rpb);
    } else {
        hipLaunchKernelGGL(pool_kernel, dim3(NBLK), dim3(256), 0, stream,
                           x, bid, wsum, wmax, n, rpb);
        hipLaunchKernelGGL(mlp_kernel, dim3(1), dim3(512), 0, stream,
                           ws, bid, W1, b1, W2, b2, wscale, n);
        hipLaunchKernelGGL(apply_kernel, dim3(NBLK), dim3(256), 0, stream,
                           x, bid, wscale, out, n, rpb);
    }
}